// Round 1
// baseline (306.003 us; speedup 1.0000x reference)
//
#include <hip/hip_runtime.h>
#include <math.h>

#define NB 16
#define NS 720
#define NC 862
#define NP 24
#define NQ 30
#define NDM 128
#define NPRED 336
#define BC (NB*NC)          /* 13792 */
#define YSTR 896            /* padded C stride for y scratch (mult of 4, >= 13*64+64) */
#define SCH 10
#define SLEN 72             /* 720/10 */
#define YOFF (23*BC)        /* mean,stdev,rstd (3*BC) + psum,psq (2*SCH*BC) */

// ---------------- stats: two-phase, deterministic (no atomics) ----------------
__global__ __launch_bounds__(256) void stats_partial_k(const float* __restrict__ x,
                                                       float* __restrict__ ws) {
    int b = blockIdx.x, ct = blockIdx.y, ch = blockIdx.z;
    int c = ct * 256 + threadIdx.x;
    if (c >= NC) return;
    const float* xp = x + ((size_t)b * NS + (size_t)ch * SLEN) * NC + c;
    float s = 0.f, sq = 0.f;
    #pragma unroll 4
    for (int i = 0; i < SLEN; ++i) {
        float v = xp[(size_t)i * NC];
        s += v; sq += v * v;
    }
    int idx = b * NC + c;
    float* ps = ws + 3 * BC;
    ps[(size_t)ch * BC + idx] = s;
    ps[(size_t)(SCH + ch) * BC + idx] = sq;
}

__global__ __launch_bounds__(256) void stats_final_k(float* __restrict__ ws) {
    int idx = blockIdx.x * 256 + threadIdx.x;
    if (idx >= BC) return;
    const float* ps = ws + 3 * BC;
    float s = 0.f, sq = 0.f;
    #pragma unroll
    for (int ch = 0; ch < SCH; ++ch) {
        s  += ps[(size_t)ch * BC + idx];
        sq += ps[(size_t)(SCH + ch) * BC + idx];
    }
    float mean  = s * (1.f / NS);
    float var   = sq * (1.f / NS) - mean * mean;
    float stdev = sqrtf(var + 1e-5f);
    ws[idx]          = mean;
    ws[BC + idx]     = stdev;
    ws[2 * BC + idx] = 1.f / stdev;
}

// ---------------- branch kernel: per-p pointwise convs (only layer l=1 matters)
// thread = one (b,c) column; weight reads are wave-uniform -> s_load + SGPR-operand FMAs.
__global__ __launch_bounds__(256) void branch_k(const float* __restrict__ x,
                                                const float* __restrict__ W1,
                                                const float* __restrict__ W2,
                                                const float* __restrict__ revw,
                                                const float* __restrict__ revb,
                                                const float* __restrict__ ws,
                                                float* __restrict__ y) {
    int p = blockIdx.x;   // 24
    int b = blockIdx.y;   // 16
    int c = blockIdx.z * 256 + threadIdx.x;
    bool act = (c < NC);
    if (!act) c = NC - 1;                     // clamp; store masked
    int idx = b * NC + c;
    float mean = ws[idx];
    float rstd = ws[2 * BC + idx];
    float aw = revw[c] * rstd;                // xn = x*aw + bw
    float bw = revb[c] - mean * aw;

    const float* xp = x + ((size_t)b * NS + p) * NC + c;
    float xs[NQ];
    #pragma unroll
    for (int q = 0; q < NQ; ++q) xs[q] = xp[(size_t)q * NP * NC] * aw + bw;

    const float* w1 = W1 + (size_t)(NP + p) * NDM * NQ;   // layer 1, phase p: [d][q]
    const float* w2 = W2 + (size_t)(NP + p) * NQ * NDM;   // layer 1, phase p: [q][d]

    float ys[NQ];
    #pragma unroll
    for (int q = 0; q < NQ; ++q) ys[q] = 0.f;

    for (int d = 0; d < NDM; ++d) {
        float hd = 0.f;
        #pragma unroll
        for (int q = 0; q < NQ; ++q) hd += w1[d * NQ + q] * xs[q];
        // exact gelu: x * 0.5 * (1 + erf(x/sqrt(2)))
        hd = hd * 0.5f * (1.f + erff(hd * 0.70710678118654752f));
        #pragma unroll
        for (int q = 0; q < NQ; ++q) ys[q] += w2[q * NDM + d] * hd;
    }

    if (act) {
        float* yp = y + ((size_t)b * NS + p) * YSTR + c;
        #pragma unroll
        for (int q = 0; q < NQ; ++q) yp[(size_t)q * NP * YSTR] = ys[q];
    }
}

// ---------------- projection GEMM (per-batch 336x862x720) + RevIN denorm epilogue
#define BM 64
#define BN 64
#define BK 16

__global__ __launch_bounds__(256) void proj_k(const float* __restrict__ pw,
                                              const float* __restrict__ pb,
                                              const float* __restrict__ revw,
                                              const float* __restrict__ revb,
                                              const float* __restrict__ ws,
                                              const float* __restrict__ y,
                                              float* __restrict__ out) {
    __shared__ float As[BK][BM];       // proj_w tile, [k][m]
    __shared__ float Bs[BK][BN];       // y tile,      [k][n]
    int nt = blockIdx.x;               // 14 c-tiles
    int mt = blockIdx.y;               // 6 pr-tiles
    int bb = blockIdx.z;               // 16 batches
    int tid = threadIdx.x;
    int tx = tid & 15;                 // n group
    int ty = tid >> 4;                 // m group
    int m0 = mt * BM, n0 = nt * BN;

    float acc[4][4];
    #pragma unroll
    for (int i = 0; i < 4; ++i)
        #pragma unroll
        for (int j = 0; j < 4; ++j) acc[i][j] = 0.f;

    for (int k0 = 0; k0 < NS; k0 += BK) {
        {   // As: 64 m x 16 k; each thread: one m row, 4 consecutive k (float4)
            int m  = tid >> 2;
            int kq = (tid & 3) * 4;
            int gm = m0 + m;
            float4 v = make_float4(0.f, 0.f, 0.f, 0.f);
            if (gm < NPRED) v = *(const float4*)(pw + (size_t)gm * NS + k0 + kq);
            As[kq + 0][m] = v.x; As[kq + 1][m] = v.y;
            As[kq + 2][m] = v.z; As[kq + 3][m] = v.w;
        }
        {   // Bs: 16 k x 64 n; each thread: one k row, 4 consecutive n (float4)
            int k  = tid >> 4;
            int nq = (tid & 15) * 4;
            float4 v = *(const float4*)(y + ((size_t)bb * NS + k0 + k) * YSTR + n0 + nq);
            *(float4*)&Bs[k][nq] = v;
        }
        __syncthreads();
        #pragma unroll
        for (int k = 0; k < BK; ++k) {
            float a[4], bv[4];
            *(float4*)a  = *(const float4*)&As[k][ty * 4];
            *(float4*)bv = *(const float4*)&Bs[k][tx * 4];
            #pragma unroll
            for (int i = 0; i < 4; ++i)
                #pragma unroll
                for (int j = 0; j < 4; ++j) acc[i][j] += a[i] * bv[j];
        }
        __syncthreads();
    }

    #pragma unroll
    for (int i = 0; i < 4; ++i) {
        int pr = m0 + ty * 4 + i;
        if (pr >= NPRED) continue;
        float bias = pb[pr];
        #pragma unroll
        for (int j = 0; j < 4; ++j) {
            int c = n0 + tx * 4 + j;
            if (c >= NC) continue;
            int idx = bb * NC + c;
            float t = (acc[i][j] + bias - revb[c]) / (revw[c] + 1e-10f);
            out[((size_t)bb * NPRED + pr) * NC + c] = t * ws[BC + idx] + ws[idx];
        }
    }
}

extern "C" void kernel_launch(void* const* d_in, const int* in_sizes, int n_in,
                              void* d_out, int out_size, void* d_ws, size_t ws_size,
                              hipStream_t stream) {
    const float* x   = (const float*)d_in[0];
    const float* W1  = (const float*)d_in[1];
    const float* W2  = (const float*)d_in[2];
    const float* pw  = (const float*)d_in[3];
    const float* pb  = (const float*)d_in[4];
    const float* rw  = (const float*)d_in[5];
    const float* rb  = (const float*)d_in[6];
    float* out = (float*)d_out;
    float* ws  = (float*)d_ws;
    float* y   = ws + YOFF;

    stats_partial_k<<<dim3(NB, 4, SCH), 256, 0, stream>>>(x, ws);
    stats_final_k<<<dim3((BC + 255) / 256), 256, 0, stream>>>(ws);
    branch_k<<<dim3(NP, NB, 4), 256, 0, stream>>>(x, W1, W2, rw, rb, ws, y);
    proj_k<<<dim3(14, 6, NB), 256, 0, stream>>>(pw, pb, rw, rb, ws, y, out);
}

// Round 2
// 219.599 us; speedup vs baseline: 1.3935x; 1.3935x over previous
//
#include <hip/hip_runtime.h>
#include <math.h>

typedef __attribute__((ext_vector_type(8))) short bf16x8;
typedef __attribute__((ext_vector_type(4))) short short4v;
typedef __attribute__((ext_vector_type(4))) float f32x4;

#define NB 16
#define NS 720
#define NC 862
#define NP 24
#define NQ 30
#define NDM 128
#define NPRED 336
#define BC (NB*NC)          /* 13792 */
#define SCH 10
#define SLEN 72             /* 720/10 */
#define SSTR 736            /* padded s-stride (bf16 elems) for y_t */
#define YOFF (23*BC)        /* floats of stats area before y_t */

__device__ __forceinline__ short f2bf(float f) {
    union { float f; unsigned u; } v; v.f = f;
    unsigned r = v.u + 0x7FFFu + ((v.u >> 16) & 1u);   // round-to-nearest-even
    return (short)(r >> 16);
}

// ---------------- stats: two-phase, deterministic ----------------
__global__ __launch_bounds__(256) void stats_partial_k(const float* __restrict__ x,
                                                       float* __restrict__ ws) {
    int b = blockIdx.x, ct = blockIdx.y, ch = blockIdx.z;
    int c = ct * 256 + threadIdx.x;
    if (c >= NC) return;
    const float* xp = x + ((size_t)b * NS + (size_t)ch * SLEN) * NC + c;
    float s = 0.f, sq = 0.f;
    #pragma unroll 4
    for (int i = 0; i < SLEN; ++i) {
        float v = xp[(size_t)i * NC];
        s += v; sq += v * v;
    }
    int idx = b * NC + c;
    float* ps = ws + 3 * BC;
    ps[(size_t)ch * BC + idx] = s;
    ps[(size_t)(SCH + ch) * BC + idx] = sq;
}

__global__ __launch_bounds__(256) void stats_final_k(float* __restrict__ ws) {
    int idx = blockIdx.x * 256 + threadIdx.x;
    if (idx >= BC) return;
    const float* ps = ws + 3 * BC;
    float s = 0.f, sq = 0.f;
    #pragma unroll
    for (int ch = 0; ch < SCH; ++ch) {
        s  += ps[(size_t)ch * BC + idx];
        sq += ps[(size_t)(SCH + ch) * BC + idx];
    }
    float mean  = s * (1.f / NS);
    float var   = sq * (1.f / NS) - mean * mean;
    float stdev = sqrtf(var + 1e-5f);
    ws[idx]          = mean;
    ws[BC + idx]     = stdev;
    ws[2 * BC + idx] = 1.f / stdev;
}

// ---------------- zero the K-pad region of y_t (s in [720,736)) ----------------
__global__ __launch_bounds__(256) void ypad_k(unsigned short* __restrict__ y_t) {
    int u = blockIdx.x * 256 + threadIdx.x;
    if (u >= NB * NC * 2) return;
    int row = u >> 1, h = u & 1;
    *(uint4*)(y_t + (size_t)row * SSTR + NS + h * 8) = make_uint4(0, 0, 0, 0);
}

// ---------------- branch: per-p MFMA  H=gelu(W1 Xs); Y^T = H^T W2^T ----------------
// LDS frag-major layout: element (row, k) at [(k>>3)*NROWS + row]*8 + (k&7)
__global__ __launch_bounds__(256) void branch_k(const float* __restrict__ x,
        const float* __restrict__ W1, const float* __restrict__ W2,
        const float* __restrict__ revw, const float* __restrict__ revb,
        const float* __restrict__ ws, unsigned short* __restrict__ y_t) {
    __shared__ short XsB[4 * 64 * 8];     // B of H-GEMM: rows=col(64), K=q(32)
    __shared__ short W1B[4 * 128 * 8];    // A of H-GEMM: rows=d(128), K=q(32)
    __shared__ short W2B[16 * 32 * 8];    // B of Y-GEMM: rows=q(32),  K=d(128)
    __shared__ short HB [16 * 64 * 8];    // A of Y-GEMM: rows=col(64),K=d(128)
    int tid = threadIdx.x;
    int c0 = blockIdx.x * 64;
    int p  = blockIdx.y;
    int b  = blockIdx.z;
    const float* w1 = W1 + (size_t)(NP + p) * NDM * NQ;   // layer 1 only (loop overwrites y)
    const float* w2 = W2 + (size_t)(NP + p) * NQ * NDM;

    {   // stage W1 [d][q] -> frag-major
        int d = tid >> 1;
        #pragma unroll
        for (int pass = 0; pass < 2; ++pass) {
            int qb = pass * 2 + (tid & 1);
            short v[8];
            #pragma unroll
            for (int j = 0; j < 8; ++j) {
                int q = qb * 8 + j;
                v[j] = f2bf(q < NQ ? w1[d * NQ + q] : 0.f);
            }
            *(bf16x8*)&W1B[(qb * 128 + d) * 8] = *(bf16x8*)v;
        }
    }
    {   // stage W2 [q][d] -> frag-major (as B of Y-GEMM: rows=q, K=d)
        for (int s = tid; s < 512; s += 256) {
            int kb = s >> 5, q = s & 31;
            short v[8];
            #pragma unroll
            for (int j = 0; j < 8; ++j)
                v[j] = f2bf(q < NQ ? w2[q * NDM + kb * 8 + j] : 0.f);
            *(bf16x8*)&W2B[(kb * 32 + q) * 8] = *(bf16x8*)v;
        }
    }
    if (tid < 240) {   // stage Xs: q = tid>>3, 8 cols each; normalize on the fly
        int q = tid >> 3, ccb = (tid & 7) * 8;
        const float* xrow = x + ((size_t)b * NS + q * NP + p) * NC;
        #pragma unroll
        for (int j = 0; j < 8; ++j) {
            int c = c0 + ccb + j;
            int ce = c < NC ? c : NC - 1;
            int idx = b * NC + ce;
            float aw = revw[ce] * ws[2 * BC + idx];
            float bw = revb[ce] - ws[idx] * aw;
            float val = (c < NC) ? xrow[ce] * aw + bw : 0.f;
            XsB[((q >> 3) * 64 + ccb + j) * 8 + (q & 7)] = f2bf(val);
        }
    } else {           // zero the q=30,31 pad slots
        int t = tid - 240;
        for (int cc = t * 4; cc < t * 4 + 4; ++cc) {
            XsB[(3 * 64 + cc) * 8 + 6] = 0;
            XsB[(3 * 64 + cc) * 8 + 7] = 0;
        }
    }
    __syncthreads();

    int w = tid >> 6, l = tid & 63, lr = l & 15, lg = l >> 4;
    f32x4 zf = {0.f, 0.f, 0.f, 0.f};

    // H = W1 @ Xs : M=128(d), N=64(col), K=32.  Wave w owns d-tiles {2w, 2w+1}.
    bf16x8 a0 = *(bf16x8*)&W1B[(lg * 128 + (2 * w) * 16 + lr) * 8];
    bf16x8 a1 = *(bf16x8*)&W1B[(lg * 128 + (2 * w + 1) * 16 + lr) * 8];
    f32x4 hc[2][4];
    #pragma unroll
    for (int ni = 0; ni < 4; ++ni) {
        bf16x8 bfr = *(bf16x8*)&XsB[(lg * 64 + ni * 16 + lr) * 8];
        hc[0][ni] = __builtin_amdgcn_mfma_f32_16x16x32_bf16(a0, bfr, zf, 0, 0, 0);
        hc[1][ni] = __builtin_amdgcn_mfma_f32_16x16x32_bf16(a1, bfr, zf, 0, 0, 0);
    }
    // gelu(exact) + write H^T into HB (rows=col, K=d)
    #pragma unroll
    for (int mi2 = 0; mi2 < 2; ++mi2) {
        int d0 = (2 * w + mi2) * 16 + 4 * lg;      // C row = d
        int kb = d0 >> 3, sub = d0 & 7;            // sub in {0,4}
        #pragma unroll
        for (int ni = 0; ni < 4; ++ni) {
            short v[4];
            #pragma unroll
            for (int r = 0; r < 4; ++r) {
                float h = hc[mi2][ni][r];
                float g = h * 0.5f * (1.f + erff(h * 0.70710678f));
                v[r] = f2bf(g);
            }
            int col = ni * 16 + lr;                // C col = column
            *(short4v*)&HB[(kb * 64 + col) * 8 + sub] = *(short4v*)v;
        }
    }
    __syncthreads();

    // Y^T = H^T @ W2^T : M=64(col), N=32(q), K=128.  Wave w owns col-tile w.
    f32x4 yacc[2] = {zf, zf};
    #pragma unroll
    for (int ks = 0; ks < 4; ++ks) {
        bf16x8 af = *(bf16x8*)&HB[((ks * 4 + lg) * 64 + w * 16 + lr) * 8];
        #pragma unroll
        for (int ni = 0; ni < 2; ++ni) {
            bf16x8 bfr = *(bf16x8*)&W2B[((ks * 4 + lg) * 32 + ni * 16 + lr) * 8];
            yacc[ni] = __builtin_amdgcn_mfma_f32_16x16x32_bf16(af, bfr, yacc[ni], 0, 0, 0);
        }
    }
    // store: C col = q = ni*16+lr; C row = col_local = w*16 + 4*lg + r
    #pragma unroll
    for (int ni = 0; ni < 2; ++ni) {
        int q = ni * 16 + lr;
        if (q < NQ) {
            #pragma unroll
            for (int r = 0; r < 4; ++r) {
                int c = c0 + w * 16 + 4 * lg + r;
                if (c < NC)
                    y_t[((size_t)(b * NC + c)) * SSTR + q * NP + p] =
                        (unsigned short)f2bf(yacc[ni][r]);
            }
        }
    }
}

// ---------------- projection: out_b = pw(336x720) @ y_b + RevIN denorm ----------------
__global__ __launch_bounds__(256) void proj_k(const float* __restrict__ pw,
        const float* __restrict__ pb, const float* __restrict__ revw,
        const float* __restrict__ revb, const float* __restrict__ ws,
        const unsigned short* __restrict__ y_t, float* __restrict__ out) {
    __shared__ short AB[4 * 64 * 8];     // A tile: rows=m(64), K=32, frag-major
    int tid = threadIdx.x;
    int n0 = blockIdx.x * 128, m0 = blockIdx.y * 64, b = blockIdx.z;
    int w = tid >> 6, l = tid & 63, lr = l & 15, lg = l >> 4;
    f32x4 zf = {0.f, 0.f, 0.f, 0.f};
    f32x4 acc[4][2];
    #pragma unroll
    for (int mi = 0; mi < 4; ++mi) { acc[mi][0] = zf; acc[mi][1] = zf; }

    int sm = tid >> 2, skb = tid & 3;
    int gm = m0 + sm;
    for (int k0 = 0; k0 < SSTR; k0 += 32) {      // 23 steps; tail zero-padded
        short v[8];
        #pragma unroll
        for (int j = 0; j < 8; ++j) {
            int k = k0 + skb * 8 + j;
            v[j] = f2bf((gm < NPRED && k < NS) ? pw[(size_t)gm * NS + k] : 0.f);
        }
        *(bf16x8*)&AB[(skb * 64 + sm) * 8] = *(bf16x8*)v;
        __syncthreads();

        // B frags straight from global y_t (16B aligned, lanes hit full 64B lines)
        union { uint4 u; bf16x8 v; } bfr[2];
        #pragma unroll
        for (int nj = 0; nj < 2; ++nj) {
            int c = n0 + (2 * w + nj) * 16 + lr;
            if (c > NC - 1) c = NC - 1;
            bfr[nj].u = *(const uint4*)(y_t + ((size_t)(b * NC + c)) * SSTR + k0 + 8 * lg);
        }
        #pragma unroll
        for (int mi = 0; mi < 4; ++mi) {
            bf16x8 af = *(bf16x8*)&AB[(lg * 64 + mi * 16 + lr) * 8];
            acc[mi][0] = __builtin_amdgcn_mfma_f32_16x16x32_bf16(af, bfr[0].v, acc[mi][0], 0, 0, 0);
            acc[mi][1] = __builtin_amdgcn_mfma_f32_16x16x32_bf16(af, bfr[1].v, acc[mi][1], 0, 0, 0);
        }
        __syncthreads();
    }

    #pragma unroll
    for (int mi = 0; mi < 4; ++mi) {
        #pragma unroll
        for (int r = 0; r < 4; ++r) {
            int pr = m0 + mi * 16 + 4 * lg + r;
            if (pr >= NPRED) continue;
            float bias = pb[pr];
            #pragma unroll
            for (int nj = 0; nj < 2; ++nj) {
                int c = n0 + (2 * w + nj) * 16 + lr;
                if (c >= NC) continue;
                int idx = b * NC + c;
                float t = (acc[mi][nj][r] + bias - revb[c]) / (revw[c] + 1e-10f);
                out[((size_t)b * NPRED + pr) * NC + c] = t * ws[BC + idx] + ws[idx];
            }
        }
    }
}

extern "C" void kernel_launch(void* const* d_in, const int* in_sizes, int n_in,
                              void* d_out, int out_size, void* d_ws, size_t ws_size,
                              hipStream_t stream) {
    const float* x   = (const float*)d_in[0];
    const float* W1  = (const float*)d_in[1];
    const float* W2  = (const float*)d_in[2];
    const float* pw  = (const float*)d_in[3];
    const float* pb  = (const float*)d_in[4];
    const float* rw  = (const float*)d_in[5];
    const float* rb  = (const float*)d_in[6];
    float* out = (float*)d_out;
    float* ws  = (float*)d_ws;
    unsigned short* y_t = (unsigned short*)(ws + YOFF);

    stats_partial_k<<<dim3(NB, 4, SCH), 256, 0, stream>>>(x, ws);
    stats_final_k<<<dim3((BC + 255) / 256), 256, 0, stream>>>(ws);
    ypad_k<<<dim3((NB * NC * 2 + 255) / 256), 256, 0, stream>>>(y_t);
    branch_k<<<dim3(14, NP, NB), 256, 0, stream>>>(x, W1, W2, rw, rb, ws, y_t);
    proj_k<<<dim3(7, 6, NB), 256, 0, stream>>>(pw, pb, rw, rb, ws, y_t, out);
}

// Round 3
// 103.766 us; speedup vs baseline: 2.9490x; 2.1163x over previous
//
#include <hip/hip_runtime.h>
#include <math.h>

typedef __attribute__((ext_vector_type(8))) short bf16x8;
typedef __attribute__((ext_vector_type(4))) short short4v;
typedef __attribute__((ext_vector_type(4))) float f32x4;

#define NB 16
#define NS 720
#define NC 862
#define NP 24
#define NQ 30
#define NDM 128
#define NPRED 336
#define BC (NB*NC)          /* 13792 */
#define SCH 10
#define SLEN 72             /* 720/10 */
#define KP 768              /* padded K: 24 p * 32 q-slots */
#define PBASE (4*BC)        /* stats partials (floats) */
#define WOFF_F (24*BC)      /* float offset of bf16 blobs */

__device__ __forceinline__ short f2bf(float f) {
    union { float f; unsigned u; } v; v.f = f;
    unsigned r = v.u + 0x7FFFu + ((v.u >> 16) & 1u);   // round-to-nearest-even
    return (short)(r >> 16);
}

// ---------------- stats: two-phase, deterministic ----------------
__global__ __launch_bounds__(256) void stats_partial_k(const float* __restrict__ x,
                                                       float* __restrict__ ws) {
    int b = blockIdx.x, ct = blockIdx.y, ch = blockIdx.z;
    int c = ct * 256 + threadIdx.x;
    if (c >= NC) return;
    const float* xp = x + ((size_t)b * NS + (size_t)ch * SLEN) * NC + c;
    float s = 0.f, sq = 0.f;
    #pragma unroll 4
    for (int i = 0; i < SLEN; ++i) {
        float v = xp[(size_t)i * NC];
        s += v; sq += v * v;
    }
    int idx = b * NC + c;
    float* ps = ws + PBASE;
    ps[(size_t)ch * BC + idx] = s;
    ps[(size_t)(SCH + ch) * BC + idx] = sq;
}

// writes AW,BW (branch normalize) and U,V (proj denorm)
__global__ __launch_bounds__(256) void stats_final_k(float* __restrict__ ws,
                                                     const float* __restrict__ revw,
                                                     const float* __restrict__ revb) {
    int idx = blockIdx.x * 256 + threadIdx.x;
    if (idx >= BC) return;
    const float* ps = ws + PBASE;
    float s = 0.f, sq = 0.f;
    #pragma unroll
    for (int ch = 0; ch < SCH; ++ch) {
        s  += ps[(size_t)ch * BC + idx];
        sq += ps[(size_t)(SCH + ch) * BC + idx];
    }
    int c = idx % NC;
    float mean  = s * (1.f / NS);
    float var   = sq * (1.f / NS) - mean * mean;
    float stdev = sqrtf(var + 1e-5f);
    float rstd  = 1.f / stdev;
    float aw = revw[c] * rstd;
    float u  = stdev / (revw[c] + 1e-10f);
    ws[idx]          = aw;                     // AW
    ws[BC + idx]     = revb[c] - mean * aw;    // BW
    ws[2 * BC + idx] = u;                      // U
    ws[3 * BC + idx] = mean - revb[c] * u;     // V
}

// ---------------- prep: bf16 weight blobs in swizzled frag-major layout ----------------
// slot(kb,row) = kb*R + (row ^ kb)
__global__ __launch_bounds__(256) void wprep_k(const float* __restrict__ W1,
                                               const float* __restrict__ W2,
                                               unsigned short* __restrict__ W1F,
                                               unsigned short* __restrict__ W2F) {
    int p = blockIdx.x, tid = threadIdx.x;
    const float* w1 = W1 + (size_t)(NP + p) * NDM * NQ;   // layer 1 only
    const float* w2 = W2 + (size_t)(NP + p) * NQ * NDM;
    #pragma unroll
    for (int pass = 0; pass < 2; ++pass) {
        int s = pass * 256 + tid;
        {   // W1F: rows=d(128), K=q(32) -> kb in [0,4)
            int kb = s >> 7, d = s & 127;
            bf16x8 v;
            #pragma unroll
            for (int j = 0; j < 8; ++j) {
                int q = kb * 8 + j;
                v[j] = f2bf(q < NQ ? w1[d * NQ + q] : 0.f);
            }
            *(bf16x8*)&W1F[((size_t)p * 4096 + (size_t)(kb * 128 + (d ^ kb)) * 8)] = v;
        }
        {   // W2F: rows=q(32), K=d(128) -> kb in [0,16)
            int kb = s >> 5, q = s & 31;
            bf16x8 v;
            #pragma unroll
            for (int j = 0; j < 8; ++j)
                v[j] = f2bf(q < NQ ? w2[q * NDM + kb * 8 + j] : 0.f);
            *(bf16x8*)&W2F[((size_t)p * 4096 + (size_t)(kb * 32 + (q ^ kb)) * 8)] = v;
        }
    }
}

// PWP[m][p*32+q] = pw[m][q*24+p] (bf16, zeros at q>=30), row stride KP
__global__ __launch_bounds__(256) void pwprep_k(const float* __restrict__ pw,
                                                unsigned short* __restrict__ PWP) {
    int t = blockIdx.x * 256 + threadIdx.x;
    if (t >= NPRED * (KP / 8)) return;
    int m = t / (KP / 8), oct = t % (KP / 8);
    bf16x8 v;
    #pragma unroll
    for (int j = 0; j < 8; ++j) {
        int r = oct * 8 + j;
        int p = r >> 5, q = r & 31;
        v[j] = f2bf(q < NQ ? pw[(size_t)m * NS + q * NP + p] : 0.f);
    }
    *(bf16x8*)&PWP[(size_t)m * KP + oct * 8] = v;
}

// ---------------- branch: per-p MFMA  H=gelu(W1 Xs); Y = W2 H (rows=q, cols=c) ----------
__global__ __launch_bounds__(256) void branch_k(const float* __restrict__ x,
        const unsigned short* __restrict__ W1F, const unsigned short* __restrict__ W2F,
        const float* __restrict__ ws, unsigned short* __restrict__ y_t) {
    __shared__ __align__(16) short XsB[4 * 64 * 8];     // B of H-GEMM: rows=c(64), K=q
    __shared__ __align__(16) short W1B[4 * 128 * 8];    // A of H-GEMM: rows=d(128), K=q
    __shared__ __align__(16) short W2B[16 * 32 * 8];    // A of Y-GEMM: rows=q(32), K=d
    __shared__ __align__(16) short HB [16 * 64 * 8];    // B of Y-GEMM: rows=c(64),  K=d
    int tid = threadIdx.x;
    int c0 = blockIdx.x * 64;
    int p  = blockIdx.y;
    int b  = blockIdx.z;

    {   // stage weights: pure 16B copies (already swizzled frag-major)
        const bf16x8* s1 = (const bf16x8*)(W1F + (size_t)p * 4096);
        const bf16x8* s2 = (const bf16x8*)(W2F + (size_t)p * 4096);
        *(bf16x8*)&W1B[(size_t)tid * 8]         = s1[tid];
        *(bf16x8*)&W1B[(size_t)(tid + 256) * 8] = s1[tid + 256];
        *(bf16x8*)&W2B[(size_t)tid * 8]         = s2[tid];
        *(bf16x8*)&W2B[(size_t)(tid + 256) * 8] = s2[tid + 256];
    }
    {   // stage Xs: lane=c (coalesced 256B global reads), one 16B LDS write/thread
        int c  = tid & 63, kb = tid >> 6;
        int cg = c0 + c;
        bool cv = cg < NC;
        int ce = cv ? cg : NC - 1;
        float aw = ws[b * NC + ce];
        float bw = ws[BC + b * NC + ce];
        const float* xb = x + ((size_t)b * NS + p) * NC + ce;
        bf16x8 v;
        #pragma unroll
        for (int j = 0; j < 8; ++j) {
            int q = kb * 8 + j;
            float val = (q < NQ && cv) ? xb[(size_t)q * NP * NC] * aw + bw : 0.f;
            v[j] = f2bf(val);
        }
        *(bf16x8*)&XsB[(size_t)(kb * 64 + (c ^ kb)) * 8] = v;
    }
    __syncthreads();

    int w = tid >> 6, l = tid & 63, lr = l & 15, lg = l >> 4;
    f32x4 zf = {0.f, 0.f, 0.f, 0.f};

    // H = W1 @ Xs : M=128(d), N=64(c), K=32. Wave w owns d-tiles {2w,2w+1}.
    bf16x8 a0 = *(const bf16x8*)&W1B[(size_t)(lg * 128 + (((2 * w) * 16 + lr) ^ lg)) * 8];
    bf16x8 a1 = *(const bf16x8*)&W1B[(size_t)(lg * 128 + (((2 * w + 1) * 16 + lr) ^ lg)) * 8];
    f32x4 hc[2][4];
    #pragma unroll
    for (int ni = 0; ni < 4; ++ni) {
        bf16x8 bfr = *(const bf16x8*)&XsB[(size_t)(lg * 64 + ((ni * 16 + lr) ^ lg)) * 8];
        hc[0][ni] = __builtin_amdgcn_mfma_f32_16x16x32_bf16(a0, bfr, zf, 0, 0, 0);
        hc[1][ni] = __builtin_amdgcn_mfma_f32_16x16x32_bf16(a1, bfr, zf, 0, 0, 0);
    }
    // gelu + write H^T into HB (rows=c, K=d)
    #pragma unroll
    for (int mi2 = 0; mi2 < 2; ++mi2) {
        int d0 = (2 * w + mi2) * 16 + 4 * lg;
        int kb = d0 >> 3, sub = d0 & 7;            // sub in {0,4}
        #pragma unroll
        for (int ni = 0; ni < 4; ++ni) {
            short4v v;
            #pragma unroll
            for (int r = 0; r < 4; ++r) {
                float h = hc[mi2][ni][r];
                v[r] = f2bf(h * 0.5f * (1.f + erff(h * 0.70710678f)));
            }
            int col = ni * 16 + lr;
            *(short4v*)&HB[(size_t)(kb * 64 + (col ^ kb)) * 8 + sub] = v;
        }
    }
    __syncthreads();

    // Y = W2 @ H : M=32(q), N=64(c), K=128. Wave w owns c-tile w.
    f32x4 yacc[2] = {zf, zf};
    #pragma unroll
    for (int ks = 0; ks < 4; ++ks) {
        int kb = ks * 4 + lg;
        bf16x8 hfr = *(const bf16x8*)&HB[(size_t)(kb * 64 + ((w * 16 + lr) ^ kb)) * 8];
        #pragma unroll
        for (int mi = 0; mi < 2; ++mi) {
            bf16x8 w2f = *(const bf16x8*)&W2B[(size_t)(kb * 32 + ((mi * 16 + lr) ^ kb)) * 8];
            yacc[mi] = __builtin_amdgcn_mfma_f32_16x16x32_bf16(w2f, hfr, yacc[mi], 0, 0, 0);
        }
    }
    // store: C col = c = w*16+lr; C row = q = mi*16 + 4*lg + r -> 8B contiguous per lane
    int cg2 = c0 + w * 16 + lr;
    if (cg2 < NC) {
        unsigned short* base = y_t + ((size_t)(b * NC + cg2)) * KP + p * 32;
        #pragma unroll
        for (int mi = 0; mi < 2; ++mi) {
            int q0 = mi * 16 + 4 * lg;
            short4v v;
            #pragma unroll
            for (int r = 0; r < 4; ++r)
                v[r] = (q0 + r < NQ) ? f2bf(yacc[mi][r]) : (short)0;
            *(short4v*)(base + q0) = v;
        }
    }
}

// ---------------- projection: out_b = PWP(336xKP) @ y_t_b^T + denorm ----------------
__global__ __launch_bounds__(256) void proj_k(const unsigned short* __restrict__ PWP,
        const float* __restrict__ pb, const float* __restrict__ ws,
        const unsigned short* __restrict__ y_t, float* __restrict__ out) {
    __shared__ __align__(16) short AB[4 * 64 * 8];     // rows=m(64), K=32, swizzled
    int tid = threadIdx.x;
    int n0 = blockIdx.x * 128, m0 = blockIdx.y * 64, b = blockIdx.z;
    int w = tid >> 6, l = tid & 63, lr = l & 15, lg = l >> 4;
    f32x4 zf = {0.f, 0.f, 0.f, 0.f};
    f32x4 acc[4][2];
    #pragma unroll
    for (int mi = 0; mi < 4; ++mi) { acc[mi][0] = zf; acc[mi][1] = zf; }

    int skb = tid >> 6, sm = tid & 63;
    int gm = m0 + sm;
    for (int k0 = 0; k0 < KP; k0 += 32) {
        union { uint4 u; bf16x8 v; } av;
        av.u = make_uint4(0, 0, 0, 0);
        if (gm < NPRED)
            av.u = *(const uint4*)(PWP + (size_t)gm * KP + k0 + skb * 8);
        __syncthreads();
        *(bf16x8*)&AB[(size_t)(skb * 64 + (sm ^ skb)) * 8] = av.v;
        __syncthreads();

        union { uint4 u; bf16x8 v; } bfr[2];
        #pragma unroll
        for (int nj = 0; nj < 2; ++nj) {
            int c = n0 + (2 * w + nj) * 16 + lr;
            int ce = c < NC ? c : NC - 1;
            bfr[nj].u = *(const uint4*)(y_t + ((size_t)(b * NC + ce)) * KP + k0 + lg * 8);
        }
        #pragma unroll
        for (int mi = 0; mi < 4; ++mi) {
            bf16x8 af = *(const bf16x8*)&AB[(size_t)(lg * 64 + ((mi * 16 + lr) ^ lg)) * 8];
            acc[mi][0] = __builtin_amdgcn_mfma_f32_16x16x32_bf16(af, bfr[0].v, acc[mi][0], 0, 0, 0);
            acc[mi][1] = __builtin_amdgcn_mfma_f32_16x16x32_bf16(af, bfr[1].v, acc[mi][1], 0, 0, 0);
        }
    }

    #pragma unroll
    for (int mi = 0; mi < 4; ++mi) {
        #pragma unroll
        for (int r = 0; r < 4; ++r) {
            int pr = m0 + mi * 16 + 4 * lg + r;
            if (pr >= NPRED) continue;
            float bias = pb[pr];
            #pragma unroll
            for (int nj = 0; nj < 2; ++nj) {
                int c = n0 + (2 * w + nj) * 16 + lr;
                if (c >= NC) continue;
                int idx = b * NC + c;
                out[((size_t)b * NPRED + pr) * NC + c] =
                    (acc[mi][nj][r] + bias) * ws[2 * BC + idx] + ws[3 * BC + idx];
            }
        }
    }
}

extern "C" void kernel_launch(void* const* d_in, const int* in_sizes, int n_in,
                              void* d_out, int out_size, void* d_ws, size_t ws_size,
                              hipStream_t stream) {
    const float* x   = (const float*)d_in[0];
    const float* W1  = (const float*)d_in[1];
    const float* W2  = (const float*)d_in[2];
    const float* pw  = (const float*)d_in[3];
    const float* pb  = (const float*)d_in[4];
    const float* rw  = (const float*)d_in[5];
    const float* rb  = (const float*)d_in[6];
    float* out = (float*)d_out;
    float* ws  = (float*)d_ws;
    unsigned short* W1F = (unsigned short*)(ws + WOFF_F);
    unsigned short* W2F = W1F + NP * 4096;
    unsigned short* PWP = W2F + NP * 4096;
    unsigned short* y_t = PWP + (size_t)NPRED * KP;

    stats_partial_k<<<dim3(NB, 4, SCH), 256, 0, stream>>>(x, ws);
    wprep_k<<<dim3(NP), 256, 0, stream>>>(W1, W2, W1F, W2F);
    pwprep_k<<<dim3((NPRED * (KP / 8) + 255) / 256), 256, 0, stream>>>(pw, PWP);
    stats_final_k<<<dim3((BC + 255) / 256), 256, 0, stream>>>(ws, rw, rb);
    branch_k<<<dim3(14, NP, NB), 256, 0, stream>>>(x, W1F, W2F, ws, y_t);
    proj_k<<<dim3(7, 6, NB), 256, 0, stream>>>(PWP, pb, ws, y_t, out);
}

// Round 4
// 93.624 us; speedup vs baseline: 3.2684x; 1.1083x over previous
//
#include <hip/hip_runtime.h>
#include <math.h>

typedef __attribute__((ext_vector_type(8))) short bf16x8;
typedef __attribute__((ext_vector_type(4))) short short4v;
typedef __attribute__((ext_vector_type(4))) float f32x4;

#define NB 16
#define NS 720
#define NC 862
#define NP 24
#define NQ 30
#define NDM 128
#define NPRED 336
#define BC (NB*NC)          /* 13792 */
#define SCH 10
#define SLEN 72             /* 720/10 */
#define KP 768              /* padded K: 24 p * 32 q-slots */
#define PBASE (4*BC)        /* stats partials (floats) */
#define WOFF_F (24*BC)      /* float offset of bf16 blobs (16B aligned) */

__device__ __forceinline__ short f2bf(float f) {
    union { float f; unsigned u; } v; v.f = f;
    unsigned r = v.u + 0x7FFFu + ((v.u >> 16) & 1u);   // round-to-nearest-even
    return (short)(r >> 16);
}

// gelu tanh-form: h * sigmoid(2*sqrt(2/pi)*(h + 0.044715 h^3)); |err vs exact| <~2e-4
__device__ __forceinline__ float gelu_f(float h) {
    float hc = fminf(fmaxf(h, -8.f), 8.f);
    float z2 = hc * hc;
    float zz = hc * (0.79788456f + 0.035677408f * z2);   // sqrt(2/pi)*(h+0.044715h^3)
    float e  = __expf(-2.f * zz);
    return h * __builtin_amdgcn_rcpf(1.f + e);
}

// ---------------- stats: two-phase, deterministic ----------------
__global__ __launch_bounds__(256) void stats_partial_k(const float* __restrict__ x,
                                                       float* __restrict__ ws) {
    int b = blockIdx.x, ct = blockIdx.y, ch = blockIdx.z;
    int c = ct * 256 + threadIdx.x;
    if (c >= NC) return;
    const float* xp = x + ((size_t)b * NS + (size_t)ch * SLEN) * NC + c;
    float s = 0.f, sq = 0.f;
    #pragma unroll 4
    for (int i = 0; i < SLEN; ++i) {
        float v = xp[(size_t)i * NC];
        s += v; sq += v * v;
    }
    int idx = b * NC + c;
    float* ps = ws + PBASE;
    ps[(size_t)ch * BC + idx] = s;
    ps[(size_t)(SCH + ch) * BC + idx] = sq;
}

__global__ __launch_bounds__(256) void stats_final_k(float* __restrict__ ws,
                                                     const float* __restrict__ revw,
                                                     const float* __restrict__ revb) {
    int idx = blockIdx.x * 256 + threadIdx.x;
    if (idx >= BC) return;
    const float* ps = ws + PBASE;
    float s = 0.f, sq = 0.f;
    #pragma unroll
    for (int ch = 0; ch < SCH; ++ch) {
        s  += ps[(size_t)ch * BC + idx];
        sq += ps[(size_t)(SCH + ch) * BC + idx];
    }
    int c = idx % NC;
    float mean  = s * (1.f / NS);
    float var   = sq * (1.f / NS) - mean * mean;
    float stdev = sqrtf(var + 1e-5f);
    float rstd  = 1.f / stdev;
    float aw = revw[c] * rstd;
    float u  = stdev / (revw[c] + 1e-10f);
    ws[idx]          = aw;                     // AW
    ws[BC + idx]     = revb[c] - mean * aw;    // BW
    ws[2 * BC + idx] = u;                      // U
    ws[3 * BC + idx] = mean - revb[c] * u;     // V
}

// ---------------- prep: frag-major bf16 weight blobs (direct global MFMA frags) ------
// A-frag layout for 16x16x32: lane l=(lr,lg) holds A[row=lr][k=8*lg+j]; one frag = 1KB.
__global__ __launch_bounds__(256) void wprep_k(const float* __restrict__ W1,
                                               const float* __restrict__ W2,
                                               unsigned short* __restrict__ W1FF,
                                               unsigned short* __restrict__ W2FF) {
    int p = blockIdx.x, tid = threadIdx.x;
    const float* w1 = W1 + (size_t)(NP + p) * NDM * NQ;   // layer 1 only
    const float* w2 = W2 + (size_t)(NP + p) * NQ * NDM;
    #pragma unroll
    for (int pass = 0; pass < 2; ++pass) {
        int s = pass * 256 + tid;                  // 512 frag-lanes per blob
        int l = s & 63, lr = l & 15, lg = l >> 4;
        {   // W1FF[dt][l]: A of H-GEMM, rows=d(dt*16+lr), k=q(8lg+j), dt in [0,8)
            int dt = s >> 6;
            int d = dt * 16 + lr;
            bf16x8 v;
            #pragma unroll
            for (int j = 0; j < 8; ++j) {
                int q = 8 * lg + j;
                v[j] = f2bf(q < NQ ? w1[d * NQ + q] : 0.f);
            }
            ((bf16x8*)(W1FF + (size_t)p * 4096))[s] = v;
        }
        {   // W2FF[mi*4+ks][l]: A of Y-GEMM, rows=q(mi*16+lr), k=d(ks*32+8lg+j)
            int g = s >> 6, mi = g >> 2, ks = g & 3;
            int q = mi * 16 + lr, k = ks * 32 + 8 * lg;
            bf16x8 v;
            #pragma unroll
            for (int j = 0; j < 8; ++j)
                v[j] = f2bf(q < NQ ? w2[q * NDM + k + j] : 0.f);
            ((bf16x8*)(W2FF + (size_t)p * 4096))[s] = v;
        }
    }
}

// PWPF[st][ks][l][j] = pw[m=st*16+lr][k: q=8lg+j, p=ks] (zeros m>=336 or q>=30)
__global__ __launch_bounds__(256) void pwprep_k(const float* __restrict__ pw,
                                                unsigned short* __restrict__ PWPF) {
    int t = blockIdx.x * 256 + threadIdx.x;
    if (t >= 24 * 24 * 64) return;
    int l = t & 63, ks = (t >> 6) % 24, st = t / (24 * 64);
    int lr = l & 15, lg = l >> 4;
    int m = st * 16 + lr;
    bf16x8 v;
    #pragma unroll
    for (int j = 0; j < 8; ++j) {
        int q = 8 * lg + j;
        v[j] = f2bf((m < NPRED && q < NQ) ? pw[(size_t)m * NS + q * NP + ks] : 0.f);
    }
    ((bf16x8*)PWPF)[t] = v;
}

// ---------------- branch: per-p MFMA  H=gelu(W1 Xs); Y = W2 H ----------------
__global__ __launch_bounds__(256) void branch_k(const float* __restrict__ x,
        const unsigned short* __restrict__ W1FF, const unsigned short* __restrict__ W2FF,
        const float* __restrict__ ws, unsigned short* __restrict__ y_t) {
    __shared__ __align__(16) short XsB[4 * 64 * 8];     // B of H-GEMM: rows=c(64), K=q
    __shared__ __align__(16) short HB [16 * 64 * 8];    // B of Y-GEMM: rows=c(64), K=d
    int tid = threadIdx.x;
    int c0 = blockIdx.x * 64;
    int p  = blockIdx.y;
    int b  = blockIdx.z;

    {   // stage Xs: lane=c (coalesced), one 16B LDS write/thread, XOR swizzle
        int c  = tid & 63, kb = tid >> 6;
        int cg = c0 + c;
        bool cv = cg < NC;
        int ce = cv ? cg : NC - 1;
        float aw = ws[b * NC + ce];
        float bw = ws[BC + b * NC + ce];
        const float* xb = x + ((size_t)b * NS + p) * NC + ce;
        bf16x8 v;
        #pragma unroll
        for (int j = 0; j < 8; ++j) {
            int q = kb * 8 + j;
            float val = (q < NQ && cv) ? xb[(size_t)q * NP * NC] * aw + bw : 0.f;
            v[j] = f2bf(val);
        }
        *(bf16x8*)&XsB[(size_t)(kb * 64 + (c ^ kb)) * 8] = v;
    }

    int w = tid >> 6, l = tid & 63, lr = l & 15, lg = l >> 4;
    f32x4 zf = {0.f, 0.f, 0.f, 0.f};
    const bf16x8* w1p = (const bf16x8*)(W1FF + (size_t)p * 4096);
    const bf16x8* w2p = (const bf16x8*)(W2FF + (size_t)p * 4096);
    // A frags direct from global (L2-hot: 224-block reuse per p)
    bf16x8 a0 = w1p[(2 * w) * 64 + l];
    bf16x8 a1 = w1p[(2 * w + 1) * 64 + l];

    __syncthreads();

    // H = W1 @ Xs : M=128(d), N=64(c), K=32. Wave w owns d-tiles {2w,2w+1}.
    f32x4 hc[2][4];
    #pragma unroll
    for (int ni = 0; ni < 4; ++ni) {
        bf16x8 bfr = *(const bf16x8*)&XsB[(size_t)(lg * 64 + ((ni * 16 + lr) ^ lg)) * 8];
        hc[0][ni] = __builtin_amdgcn_mfma_f32_16x16x32_bf16(a0, bfr, zf, 0, 0, 0);
        hc[1][ni] = __builtin_amdgcn_mfma_f32_16x16x32_bf16(a1, bfr, zf, 0, 0, 0);
    }
    // gelu + write H^T into HB (rows=c, K=d), XOR swizzle
    #pragma unroll
    for (int mi2 = 0; mi2 < 2; ++mi2) {
        int d0 = (2 * w + mi2) * 16 + 4 * lg;
        int kb = d0 >> 3, sub = d0 & 7;            // sub in {0,4}
        #pragma unroll
        for (int ni = 0; ni < 4; ++ni) {
            short4v v;
            #pragma unroll
            for (int r = 0; r < 4; ++r)
                v[r] = f2bf(gelu_f(hc[mi2][ni][r]));
            int col = ni * 16 + lr;
            *(short4v*)&HB[(size_t)(kb * 64 + (col ^ kb)) * 8 + sub] = v;
        }
    }
    __syncthreads();

    // Y = W2 @ H : M=32(q), N=64(c), K=128. Wave w owns c-tile w.
    f32x4 yacc[2] = {zf, zf};
    #pragma unroll
    for (int ks = 0; ks < 4; ++ks) {
        int kb = ks * 4 + lg;
        bf16x8 hfr = *(const bf16x8*)&HB[(size_t)(kb * 64 + ((w * 16 + lr) ^ kb)) * 8];
        #pragma unroll
        for (int mi = 0; mi < 2; ++mi) {
            bf16x8 w2f = w2p[(mi * 4 + ks) * 64 + l];
            yacc[mi] = __builtin_amdgcn_mfma_f32_16x16x32_bf16(w2f, hfr, yacc[mi], 0, 0, 0);
        }
    }
    // store: c = w*16+lr; q = mi*16+4lg+r -> one 8B store per mi (zeros fill q>=30)
    int cg2 = c0 + w * 16 + lr;
    if (cg2 < NC) {
        unsigned short* base = y_t + ((size_t)(b * NC + cg2)) * KP + p * 32;
        #pragma unroll
        for (int mi = 0; mi < 2; ++mi) {
            int q0 = mi * 16 + 4 * lg;
            short4v v;
            #pragma unroll
            for (int r = 0; r < 4; ++r)
                v[r] = (q0 + r < NQ) ? f2bf(yacc[mi][r]) : (short)0;
            *(short4v*)(base + q0) = v;
        }
    }
}

// ---------------- projection: barrier-free, LDS-free; A/B frags direct from L2 -------
__global__ __launch_bounds__(256) void proj_k(const unsigned short* __restrict__ PWPF,
        const float* __restrict__ pb, const float* __restrict__ ws,
        const unsigned short* __restrict__ y_t, float* __restrict__ out) {
    int tid = threadIdx.x;
    int n0 = blockIdx.x * 128, m0 = blockIdx.y * 64, b = blockIdx.z;
    int w = tid >> 6, l = tid & 63, lr = l & 15, lg = l >> 4;
    int st0 = m0 >> 4;
    f32x4 zf = {0.f, 0.f, 0.f, 0.f};
    f32x4 acc[4][2];
    #pragma unroll
    for (int mi = 0; mi < 4; ++mi) { acc[mi][0] = zf; acc[mi][1] = zf; }

    const unsigned short* ytb = y_t + (size_t)b * NC * KP;
    int cA = n0 + 2 * w * 16 + lr;        if (cA > NC - 1) cA = NC - 1;
    int cB = n0 + (2 * w + 1) * 16 + lr;  if (cB > NC - 1) cB = NC - 1;
    const unsigned short* rowA = ytb + (size_t)cA * KP + lg * 8;
    const unsigned short* rowB = ytb + (size_t)cB * KP + lg * 8;
    const bf16x8* apb = (const bf16x8*)PWPF + (size_t)st0 * 24 * 64 + l;

    union u16x8 { uint4 u; bf16x8 v; };
    bf16x8 af0[4], af1[4];
    u16x8 b00, b01, b10, b11;

#define LOADF(AF, B0, B1, KS) do {                                   \
        AF[0] = apb[(0 * 24 + (KS)) * 64];                           \
        AF[1] = apb[(1 * 24 + (KS)) * 64];                           \
        AF[2] = apb[(2 * 24 + (KS)) * 64];                           \
        AF[3] = apb[(3 * 24 + (KS)) * 64];                           \
        B0.u = *(const uint4*)(rowA + (KS) * 32);                    \
        B1.u = *(const uint4*)(rowB + (KS) * 32); } while (0)
#define MM(AF, B0, B1) do {                                          \
        _Pragma("unroll")                                            \
        for (int mi = 0; mi < 4; ++mi) {                             \
            acc[mi][0] = __builtin_amdgcn_mfma_f32_16x16x32_bf16(AF[mi], B0.v, acc[mi][0], 0, 0, 0); \
            acc[mi][1] = __builtin_amdgcn_mfma_f32_16x16x32_bf16(AF[mi], B1.v, acc[mi][1], 0, 0, 0); \
        } } while (0)

    LOADF(af0, b00, b01, 0);
    #pragma unroll
    for (int ks = 0; ks < 24; ks += 2) {
        LOADF(af1, b10, b11, ks + 1);
        MM(af0, b00, b01);
        if (ks + 2 < 24) LOADF(af0, b00, b01, ks + 2);
        MM(af1, b10, b11);
    }
#undef LOADF
#undef MM

    #pragma unroll
    for (int mi = 0; mi < 4; ++mi) {
        #pragma unroll
        for (int r = 0; r < 4; ++r) {
            int pr = m0 + mi * 16 + 4 * lg + r;
            if (pr >= NPRED) continue;
            float bias = pb[pr];
            #pragma unroll
            for (int nj = 0; nj < 2; ++nj) {
                int c = n0 + (2 * w + nj) * 16 + lr;
                if (c >= NC) continue;
                int idx = b * NC + c;
                out[((size_t)b * NPRED + pr) * NC + c] =
                    (acc[mi][nj][r] + bias) * ws[2 * BC + idx] + ws[3 * BC + idx];
            }
        }
    }
}

extern "C" void kernel_launch(void* const* d_in, const int* in_sizes, int n_in,
                              void* d_out, int out_size, void* d_ws, size_t ws_size,
                              hipStream_t stream) {
    const float* x   = (const float*)d_in[0];
    const float* W1  = (const float*)d_in[1];
    const float* W2  = (const float*)d_in[2];
    const float* pw  = (const float*)d_in[3];
    const float* pb  = (const float*)d_in[4];
    const float* rw  = (const float*)d_in[5];
    const float* rb  = (const float*)d_in[6];
    float* out = (float*)d_out;
    float* ws  = (float*)d_ws;
    unsigned short* W1FF = (unsigned short*)(ws + WOFF_F);
    unsigned short* W2FF = W1FF + NP * 4096;
    unsigned short* PWPF = W2FF + NP * 4096;
    unsigned short* y_t  = PWPF + 24 * 24 * 64 * 8;

    stats_partial_k<<<dim3(NB, 4, SCH), 256, 0, stream>>>(x, ws);
    wprep_k<<<dim3(NP), 256, 0, stream>>>(W1, W2, W1FF, W2FF);
    pwprep_k<<<dim3((24 * 24 * 64 + 255) / 256), 256, 0, stream>>>(pw, PWPF);
    stats_final_k<<<dim3((BC + 255) / 256), 256, 0, stream>>>(ws, rw, rb);
    branch_k<<<dim3(14, NP, NB), 256, 0, stream>>>(x, W1FF, W2FF, ws, y_t);
    proj_k<<<dim3(7, 6, NB), 256, 0, stream>>>(PWPF, pb, ws, y_t, out);
}